// Round 4
// baseline (276.182 us; speedup 1.0000x reference)
//
#include <hip/hip_runtime.h>
#include <stdint.h>

// Dyna_Dec: out[b,d,l] = sum_c x[b,c,l] * w[l,c,d] + bias[l,d]
// B=128, C=32, L=4096. fp32 in/out.
//
// R6 (88us): W lane-scattered -> L1 serialization.
// R7 (104us): LDS staging fixed scatter; acc[8][8] spilled (WRITE +39MB).
// R8 (115us): spill fixed; serial convoy per chunk, no overlap.
// R9 (71us): double-buffer + global_load_lds(16) + pre-swizzled source.
//   Conflicts negligible (0.06 cyc/read). Residual: __syncthreads =
//   s_waitcnt vmcnt(0) drain right after issuing stage/xload -> every
//   phase eats full load latency. VALUBusy 22%.
//
// R10: counted vmcnt (T4), never drain-to-0 mid-loop.
//   Phase t: WAIT(stage(t)) ; s_barrier ; sched_barrier(0) ;
//            stage(t+1) ; [even: xload2(t+2,t+3)] ; compute(t).
//   - stage(t) issued mid phase t-1 -> 1 phase cover (W L2-resident:
//     grid keeps all 32 b-blocks of an l-chunk on one XCD).
//   - x pair-loaded 2 phases ahead into 2 rotating reg sets (static
//     indexing, no scratch). ~1300cy cover for HBM x stream.
//   - FIFO counts (order pinned by sched_barrier between stage/xload):
//     even phases vmcnt(0) [all outstanding >=1 phase old], odd phases
//     vmcnt(16) [16 x-loads from phase t-1 may stay in flight].
//   - WAR safe: stage(t+1) writes the buffer read in phase t-1; issued
//     only after barrier(t), when all waves consumed those reads.

namespace {

constexpr int kC  = 32;
constexpr int kL  = 4096;
constexpr int kNB = 4;   // batches per thread
constexpr int kND = 8;   // d-channels per thread
constexpr int kCC = 2;   // c's per staged chunk
constexpr int kLB = 64;  // l-positions per block
constexpr int kChunkFloats = kLB * kCC * kC;      // 4096 floats = 16 KB

__device__ __forceinline__ void async_ld16(const float* g, float* l) {
    __builtin_amdgcn_global_load_lds(
        (__attribute__((address_space(1))) const void*)g,
        (__attribute__((address_space(3))) void*)l, 16, 0, 0);
}

#define WAITV0()  asm volatile("s_waitcnt vmcnt(0)" ::: "memory")
#define WAITV16() asm volatile("s_waitcnt vmcnt(16)" ::: "memory")
#define SCHEDFENCE() __builtin_amdgcn_sched_barrier(0)
#define BARRIER() do { __builtin_amdgcn_s_barrier(); SCHEDFENCE(); } while (0)

__global__ __launch_bounds__(256, 4)
void dyna_dec(const float* __restrict__ x,
              const float* __restrict__ w,
              const float* __restrict__ bias,
              float* __restrict__ out) {
    __shared__ __align__(16) float ldsA[kChunkFloats];
    __shared__ __align__(16) float ldsB[kChunkFloats];

    const int tid = threadIdx.x;
    const int lt  = tid & 63;          // lane = l within chunk (coalescing dim)
    const int dg  = tid >> 6;          // wave = d-group 0..3
    const int l   = blockIdx.x * kLB + lt;      // gridDim.x = 64
    const int b0  = blockIdx.y * kNB;           // gridDim.y = 32
    const int d0  = dg * kND;

    const float* xp = x + (size_t)b0 * (kC * kL) + l;
    const float* wb = w + (size_t)blockIdx.x * kLB * (kC * kC);

    // Staging geometry: 1024 16B-slots per chunk. Wave dg, call k, lane lt
    // fills slot s = dg*256 + k*64 + lt (DMA: uniform base + lane*16).
    // Slot s holds W[ls, cb*kCC+cs, 4*(dsl^(ls&7)) .. +4) where
    // ls = s>>4, cs = (s>>3)&1, dsl = s&7  (source pre-swizzled).
    int goff[4];
    const int ldsbase = dg * 1024;
#pragma unroll
    for (int k = 0; k < 4; ++k) {
        const int s   = dg * 256 + k * 64 + lt;
        const int ls  = s >> 4;
        const int cs  = (s >> 3) & 1;
        const int dsl = s & 7;
        goff[k] = ls * (kC * kC) + cs * kC + ((dsl ^ (ls & 7)) << 2);
    }

    auto stage = [&](float* buf, int cb) {  // 4 VMEM ops
#pragma unroll
        for (int k = 0; k < 4; ++k)
            async_ld16(wb + cb * (kCC * kC) + goff[k], buf + ldsbase + k * 256);
    };

    // x register sets: 2 sets x 2 chunks x kCC x kNB (all static indexing)
    float xr0[2][kCC][kNB], xr1[2][kCC][kNB];
    auto xload2 = [&](float (&xr)[2][kCC][kNB], int chunk0) {  // 16 VMEM ops
#pragma unroll
        for (int h = 0; h < 2; ++h)
#pragma unroll
            for (int c = 0; c < kCC; ++c)
#pragma unroll
                for (int i = 0; i < kNB; ++i)
                    xr[h][c][i] = xp[(size_t)i * (kC * kL) +
                                     (size_t)((chunk0 + h) * kCC + c) * kL];
    };

    float acc[kNB][kND];
#pragma unroll
    for (int i = 0; i < kNB; ++i)
#pragma unroll
        for (int j = 0; j < kND; ++j) acc[i][j] = 0.0f;

    auto compute = [&](const float* buf, const float (&xr)[kCC][kNB]) {
#pragma unroll
        for (int c = 0; c < kCC; ++c) {
            const int sl0 = lt * 16 + c * 8 + ((2 * dg) ^ (lt & 7));
            const int sl1 = lt * 16 + c * 8 + ((2 * dg + 1) ^ (lt & 7));
            const float4 w0 = *reinterpret_cast<const float4*>(buf + sl0 * 4);
            const float4 w1 = *reinterpret_cast<const float4*>(buf + sl1 * 4);
#pragma unroll
            for (int i = 0; i < kNB; ++i) {
                const float xv = xr[c][i];
                acc[i][0] += xv * w0.x;
                acc[i][1] += xv * w0.y;
                acc[i][2] += xv * w0.z;
                acc[i][3] += xv * w0.w;
                acc[i][4] += xv * w1.x;
                acc[i][5] += xv * w1.y;
                acc[i][6] += xv * w1.z;
                acc[i][7] += xv * w1.w;
            }
        }
    };

    // Prologue: chunk 0 staged, x chunks {0,1} in flight.
    stage(ldsA, 0);
    SCHEDFENCE();
    xload2(xr0, 0);

    // 16 chunks, phases t=0..15. Chunk t: buf = A/B by t&1,
    // x set = xr0/xr1 by (t>>1)&1, half = t&1.
#pragma unroll 1
    for (int q = 0; q < 3; ++q) {
        const int t0 = 4 * q;
        // t = t0 (even)
        WAITV0(); BARRIER();
        stage(ldsB, t0 + 1); SCHEDFENCE(); xload2(xr1, t0 + 2);
        compute(ldsA, xr0[0]);
        // t = t0+1 (odd)
        WAITV16(); BARRIER();
        stage(ldsA, t0 + 2);
        compute(ldsB, xr0[1]);
        // t = t0+2 (even)
        WAITV0(); BARRIER();
        stage(ldsB, t0 + 3); SCHEDFENCE(); xload2(xr0, t0 + 4);
        compute(ldsA, xr1[0]);
        // t = t0+3 (odd)
        WAITV16(); BARRIER();
        stage(ldsA, t0 + 4);
        compute(ldsB, xr1[1]);
    }
    // Tail: t = 12..15 (chunk 12 staged + x chunks {12,13} loaded in q=2)
    WAITV0(); BARRIER();
    stage(ldsB, 13); SCHEDFENCE(); xload2(xr1, 14);
    compute(ldsA, xr0[0]);
    WAITV16(); BARRIER();
    stage(ldsA, 14);
    compute(ldsB, xr0[1]);
    WAITV0(); BARRIER();
    stage(ldsB, 15);
    compute(ldsA, xr1[0]);
    WAITV0(); BARRIER();
    compute(ldsB, xr1[1]);

    // Epilogue: bias + coalesced store.
    const float4 b0v = *reinterpret_cast<const float4*>(bias + (size_t)l * kC + d0);
    const float4 b1v = *reinterpret_cast<const float4*>(bias + (size_t)l * kC + d0 + 4);
    const float bv[kND] = {b0v.x, b0v.y, b0v.z, b0v.w, b1v.x, b1v.y, b1v.z, b1v.w};

#pragma unroll
    for (int i = 0; i < kNB; ++i) {
        float* op = out + (size_t)(b0 + i) * (kC * kL) + l;
#pragma unroll
        for (int j = 0; j < kND; ++j)
            op[(size_t)(d0 + j) * kL] = acc[i][j] + bv[j];  // coalesced over l
    }
}

}  // namespace

extern "C" void kernel_launch(void* const* d_in, const int* in_sizes, int n_in,
                              void* d_out, int out_size, void* d_ws, size_t ws_size,
                              hipStream_t stream) {
    // inputs: 0=x (B,C,H,W) fp32, 1=px (unused), 2=weight (L*C, C) fp32,
    //         3=bias (L*C) fp32
    const float* x    = (const float*)d_in[0];
    const float* wgt  = (const float*)d_in[2];
    const float* bias = (const float*)d_in[3];
    float* out = (float*)d_out;

    dim3 grid(kL / 64, 128 / kNB);  // 64 x 32 = 2048 blocks
    dim3 block(256);
    hipLaunchKernelGGL(dyna_dec, grid, block, 0, stream, x, wgt, bias, out);
}

// Round 5
// 169.360 us; speedup vs baseline: 1.6307x; 1.6307x over previous
//
#include <hip/hip_runtime.h>
#include <stdint.h>

// Dyna_Dec: out[b,d,l] = sum_c x[b,c,l] * w[l,c,d] + bias[l,d]
// B=128, C=32, L=4096. fp32 in/out.
//
// R6 (88us): W lane-scattered -> L1 serialization.
// R7 (104us): LDS staging fixed scatter; acc[8][8] spilled.
// R8 (115us): spill fixed; serial convoy, no overlap.
// R9 (71us): dbuf + global_load_lds(16) + pre-swizzled src. Residual:
//   __syncthreads = vmcnt(0) drain right after issuing stage+xload.
// R10 (182us): counted-vmcnt schedule, but 3-D x arrays passed as
//   sub-array refs -> SROA failed -> scratch (WRITE 64->295MB). Schedule
//   untested; implementation invalid (rule #20).
//
// R11: same counted-vmcnt schedule, spill-proof codegen:
//   - x sets are two 2-D arrays x0/x1, only touched via macros on the
//     NAMES, constant indices only, never passed by reference.
//   - 16 phases explicitly listed. Phase t:
//       s_waitcnt vmcnt(8) ; s_barrier ; stage(t+1) ; fence ;
//       compute(t) + xload(X[t&1], t+2)
//     Per-wave VMEM FIFO at phase top = [stage(t) x4, xload x8] ->
//     vmcnt(8) completes stage(t) (oldest-first), leaves x in flight.
//     => W-stage gets 1 phase of cover, x gets ~2 phases.
//   - sched_barrier(0) pins VMEM issue order (FIFO count soundness).
//   - WAR on LDS: barrier (ds_reads consumed into FMAs before it).
//     WAR on x regs: same-wave in-order issue.

namespace {

constexpr int kC  = 32;
constexpr int kL  = 4096;
constexpr int kNB = 4;   // batches per thread
constexpr int kND = 8;   // d-channels per thread
constexpr int kCC = 2;   // c's per staged chunk
constexpr int kLB = 64;  // l-positions per block
constexpr int kChunkFloats = kLB * kCC * kC;      // 4096 floats = 16 KB

__device__ __forceinline__ void async_ld16(const float* g, float* l) {
    __builtin_amdgcn_global_load_lds(
        (__attribute__((address_space(1))) const void*)g,
        (__attribute__((address_space(3))) void*)l, 16, 0, 0);
}

#define SCHEDFENCE() __builtin_amdgcn_sched_barrier(0)
#define WAITV(N) asm volatile("s_waitcnt vmcnt(" #N ")" ::: "memory")
#define BAR() do { __builtin_amdgcn_s_barrier(); SCHEDFENCE(); } while (0)

__global__ __launch_bounds__(256, 4)
void dyna_dec(const float* __restrict__ x,
              const float* __restrict__ w,
              const float* __restrict__ bias,
              float* __restrict__ out) {
    __shared__ __align__(16) float ldsA[kChunkFloats];
    __shared__ __align__(16) float ldsB[kChunkFloats];

    const int tid = threadIdx.x;
    const int lt  = tid & 63;          // lane = l within chunk (coalescing dim)
    const int dg  = tid >> 6;          // wave = d-group 0..3
    const int l   = blockIdx.x * kLB + lt;      // gridDim.x = 64
    const int b0  = blockIdx.y * kNB;           // gridDim.y = 32
    const int d0  = dg * kND;

    const float* xp = x + (size_t)b0 * (kC * kL) + l;
    const float* wb = w + (size_t)blockIdx.x * kLB * (kC * kC);

    // Staging geometry (verified R9/R10, absmax 0): 1024 16B-slots/chunk.
    // Wave dg, call k, lane lt fills slot s = dg*256 + k*64 + lt (DMA:
    // uniform base + lane*16). Slot s holds W[ls, cb*kCC+cs,
    // 4*(dsl^(ls&7))..+4) with ls=s>>4, cs=(s>>3)&1, dsl=s&7.
    int goff[4];
    const int ldsbase = dg * 1024;
#pragma unroll
    for (int k = 0; k < 4; ++k) {
        const int s   = dg * 256 + k * 64 + lt;
        const int ls  = s >> 4;
        const int cs  = (s >> 3) & 1;
        const int dsl = s & 7;
        goff[k] = ls * (kC * kC) + cs * kC + ((dsl ^ (ls & 7)) << 2);
    }

#define STAGE(BUF, CB) do {                                                  \
    _Pragma("unroll")                                                        \
    for (int k_ = 0; k_ < 4; ++k_)                                           \
        async_ld16(wb + (CB) * (kCC * kC) + goff[k_],                        \
                   (BUF) + ldsbase + k_ * 256);                              \
} while (0)

    float x0[kCC][kNB], x1[kCC][kNB];

#define XLOAD(XR, CB) do {                                                   \
    _Pragma("unroll")                                                        \
    for (int c_ = 0; c_ < kCC; ++c_)                                         \
        _Pragma("unroll")                                                    \
        for (int i_ = 0; i_ < kNB; ++i_)                                     \
            XR[c_][i_] = xp[(size_t)i_ * (kC * kL) +                         \
                            (size_t)((CB) * kCC + c_) * kL];                 \
} while (0)

    float acc[kNB][kND];
#pragma unroll
    for (int i = 0; i < kNB; ++i)
#pragma unroll
        for (int j = 0; j < kND; ++j) acc[i][j] = 0.0f;

#define COMPUTE(BUF, XR) do {                                                \
    _Pragma("unroll")                                                        \
    for (int c_ = 0; c_ < kCC; ++c_) {                                       \
        const int sl0_ = lt * 16 + c_ * 8 + ((2 * dg) ^ (lt & 7));           \
        const int sl1_ = lt * 16 + c_ * 8 + ((2 * dg + 1) ^ (lt & 7));       \
        const float4 w0_ =                                                   \
            *reinterpret_cast<const float4*>((BUF) + sl0_ * 4);              \
        const float4 w1_ =                                                   \
            *reinterpret_cast<const float4*>((BUF) + sl1_ * 4);              \
        _Pragma("unroll")                                                    \
        for (int i_ = 0; i_ < kNB; ++i_) {                                   \
            const float xv_ = XR[c_][i_];                                    \
            acc[i_][0] += xv_ * w0_.x;  acc[i_][1] += xv_ * w0_.y;           \
            acc[i_][2] += xv_ * w0_.z;  acc[i_][3] += xv_ * w0_.w;           \
            acc[i_][4] += xv_ * w1_.x;  acc[i_][5] += xv_ * w1_.y;           \
            acc[i_][6] += xv_ * w1_.z;  acc[i_][7] += xv_ * w1_.w;           \
        }                                                                    \
    }                                                                        \
} while (0)

    // Prologue: stage chunk 0, x chunks 0 and 1 in flight.
    STAGE(ldsA, 0); SCHEDFENCE();
    XLOAD(x0, 0);
    XLOAD(x1, 1); SCHEDFENCE();

    // Phase 0 (outstanding 20: stage0 x4 oldest -> vmcnt(16) completes it)
    WAITV(16); BAR();
    STAGE(ldsB, 1); SCHEDFENCE();
    COMPUTE(ldsA, x0); XLOAD(x0, 2); SCHEDFENCE();

#define PHASE(T, BUFC, BUFN, XS) do {                                        \
    WAITV(8); BAR();                                                         \
    STAGE(BUFN, (T) + 1); SCHEDFENCE();                                      \
    COMPUTE(BUFC, XS); XLOAD(XS, (T) + 2); SCHEDFENCE();                     \
} while (0)

    PHASE(1,  ldsB, ldsA, x1);
    PHASE(2,  ldsA, ldsB, x0);
    PHASE(3,  ldsB, ldsA, x1);
    PHASE(4,  ldsA, ldsB, x0);
    PHASE(5,  ldsB, ldsA, x1);
    PHASE(6,  ldsA, ldsB, x0);
    PHASE(7,  ldsB, ldsA, x1);
    PHASE(8,  ldsA, ldsB, x0);
    PHASE(9,  ldsB, ldsA, x1);
    PHASE(10, ldsA, ldsB, x0);
    PHASE(11, ldsB, ldsA, x1);
    PHASE(12, ldsA, ldsB, x0);
    PHASE(13, ldsB, ldsA, x1);

    // Phase 14: stage chunk 15, no further x.
    WAITV(8); BAR();
    STAGE(ldsB, 15); SCHEDFENCE();
    COMPUTE(ldsA, x0); SCHEDFENCE();

    // Phase 15: drain, compute last chunk.
    WAITV(0); BAR();
    COMPUTE(ldsB, x1);

    // Epilogue: bias + coalesced store.
    const float4 b0v = *reinterpret_cast<const float4*>(bias + (size_t)l * kC + d0);
    const float4 b1v = *reinterpret_cast<const float4*>(bias + (size_t)l * kC + d0 + 4);
    const float bv[kND] = {b0v.x, b0v.y, b0v.z, b0v.w, b1v.x, b1v.y, b1v.z, b1v.w};

#pragma unroll
    for (int i = 0; i < kNB; ++i) {
        float* op = out + (size_t)(b0 + i) * (kC * kL) + l;
#pragma unroll
        for (int j = 0; j < kND; ++j)
            op[(size_t)(d0 + j) * kL] = acc[i][j] + bv[j];  // coalesced over l
    }

#undef STAGE
#undef XLOAD
#undef COMPUTE
#undef PHASE
}

}  // namespace

extern "C" void kernel_launch(void* const* d_in, const int* in_sizes, int n_in,
                              void* d_out, int out_size, void* d_ws, size_t ws_size,
                              hipStream_t stream) {
    // inputs: 0=x (B,C,H,W) fp32, 1=px (unused), 2=weight (L*C, C) fp32,
    //         3=bias (L*C) fp32
    const float* x    = (const float*)d_in[0];
    const float* wgt  = (const float*)d_in[2];
    const float* bias = (const float*)d_in[3];
    float* out = (float*)d_out;

    dim3 grid(kL / 64, 128 / kNB);  // 64 x 32 = 2048 blocks
    dim3 block(256);
    hipLaunchKernelGGL(dyna_dec, grid, block, 0, stream, x, wgt, bias, out);
}

// Round 6
// 151.102 us; speedup vs baseline: 1.8278x; 1.1208x over previous
//
#include <hip/hip_runtime.h>
#include <stdint.h>

// Dyna_Dec: out[b,d,l] = sum_c x[b,c,l] * w[l,c,d] + bias[l,d]
// B=128, C=32, L=4096. fp32 in/out.
//
// R6 (88us): W lane-scattered -> L1 serialization.
// R7 (104us): LDS staging fixed scatter; acc[8][8]+staging temps spilled.
// R8 (115us): spill fixed; serial convoy, no overlap.
// R9 (71us): dbuf + global_load_lds(16) + pre-swizzled src.
// R10 (182us): counted vmcnt, but sub-array refs -> scratch. Invalid.
// R11 (74.6us): counted vmcnt, spill-free (VGPR 48, WRITE 64MB exact).
//   == R9 within noise -> sync-schedule theory FALSIFIED. Remaining wall:
//   tiny phases (64 FMA between barriers) vs fixed per-phase latency
//   (barrier + L2 stage + ds_read) at 33% occ, and ~60% non-FMA issue
//   overhead per phase.
//
// R12: same schedule, DOUBLE the register tile. kNB 4->8: acc[8][8]=64
//   regs + 2 x-sets (32) ~= 120 VGPR < 128 cap -- viable now that staging
//   is DMA (no VGPR round-trip; R7's spill source is gone). Halves:
//   barriers/output, W-stage redundancy (32x->16x), x wave-loads/FMA,
//   total phases across grid. Grid 64x16=1024 = exactly 4 blocks/CU
//   (LDS 128/160 KB, VGPR 2048/2048). Waits re-derived: steady vmcnt(16)
//   completes stage(t), leaves the 16 younger x-loads in flight (x RAW
//   is compiler-protected anyway; counts only protect LDS DMA).

namespace {

constexpr int kC  = 32;
constexpr int kL  = 4096;
constexpr int kNB = 8;   // batches per thread
constexpr int kND = 8;   // d-channels per thread
constexpr int kCC = 2;   // c's per staged chunk
constexpr int kLB = 64;  // l-positions per block
constexpr int kChunkFloats = kLB * kCC * kC;      // 4096 floats = 16 KB

__device__ __forceinline__ void async_ld16(const float* g, float* l) {
    __builtin_amdgcn_global_load_lds(
        (__attribute__((address_space(1))) const void*)g,
        (__attribute__((address_space(3))) void*)l, 16, 0, 0);
}

#define SCHEDFENCE() __builtin_amdgcn_sched_barrier(0)
#define WAITV(N) asm volatile("s_waitcnt vmcnt(" #N ")" ::: "memory")
#define BAR() do { __builtin_amdgcn_s_barrier(); SCHEDFENCE(); } while (0)

__global__ __launch_bounds__(256, 4)
void dyna_dec(const float* __restrict__ x,
              const float* __restrict__ w,
              const float* __restrict__ bias,
              float* __restrict__ out) {
    __shared__ __align__(16) float ldsA[kChunkFloats];
    __shared__ __align__(16) float ldsB[kChunkFloats];

    const int tid = threadIdx.x;
    const int lt  = tid & 63;          // lane = l within chunk (coalescing dim)
    const int dg  = tid >> 6;          // wave = d-group 0..3
    const int l   = blockIdx.x * kLB + lt;      // gridDim.x = 64
    const int b0  = blockIdx.y * kNB;           // gridDim.y = 16
    const int d0  = dg * kND;

    const float* xp = x + (size_t)b0 * (kC * kL) + l;
    const float* wb = w + (size_t)blockIdx.x * kLB * (kC * kC);

    // Staging geometry (verified R9/R11, absmax 0): 1024 16B-slots/chunk.
    // Wave dg, call k, lane lt fills slot s = dg*256 + k*64 + lt (DMA:
    // uniform base + lane*16). Slot s holds W[ls, cb*kCC+cs,
    // 4*(dsl^(ls&7))..+4) with ls=s>>4, cs=(s>>3)&1, dsl=s&7.
    int goff[4];
    const int ldsbase = dg * 1024;
#pragma unroll
    for (int k = 0; k < 4; ++k) {
        const int s   = dg * 256 + k * 64 + lt;
        const int ls  = s >> 4;
        const int cs  = (s >> 3) & 1;
        const int dsl = s & 7;
        goff[k] = ls * (kC * kC) + cs * kC + ((dsl ^ (ls & 7)) << 2);
    }

#define STAGE(BUF, CB) do {                                                  \
    _Pragma("unroll")                                                        \
    for (int k_ = 0; k_ < 4; ++k_)                                           \
        async_ld16(wb + (CB) * (kCC * kC) + goff[k_],                        \
                   (BUF) + ldsbase + k_ * 256);                              \
} while (0)

    float x0[kCC][kNB], x1[kCC][kNB];

#define XLOAD(XR, CB) do {                                                   \
    _Pragma("unroll")                                                        \
    for (int c_ = 0; c_ < kCC; ++c_)                                         \
        _Pragma("unroll")                                                    \
        for (int i_ = 0; i_ < kNB; ++i_)                                     \
            XR[c_][i_] = xp[(size_t)i_ * (kC * kL) +                         \
                            (size_t)((CB) * kCC + c_) * kL];                 \
} while (0)

    float acc[kNB][kND];
#pragma unroll
    for (int i = 0; i < kNB; ++i)
#pragma unroll
        for (int j = 0; j < kND; ++j) acc[i][j] = 0.0f;

#define COMPUTE(BUF, XR) do {                                                \
    _Pragma("unroll")                                                        \
    for (int c_ = 0; c_ < kCC; ++c_) {                                       \
        const int sl0_ = lt * 16 + c_ * 8 + ((2 * dg) ^ (lt & 7));           \
        const int sl1_ = lt * 16 + c_ * 8 + ((2 * dg + 1) ^ (lt & 7));       \
        const float4 w0_ =                                                   \
            *reinterpret_cast<const float4*>((BUF) + sl0_ * 4);              \
        const float4 w1_ =                                                   \
            *reinterpret_cast<const float4*>((BUF) + sl1_ * 4);              \
        _Pragma("unroll")                                                    \
        for (int i_ = 0; i_ < kNB; ++i_) {                                   \
            const float xv_ = XR[c_][i_];                                    \
            acc[i_][0] += xv_ * w0_.x;  acc[i_][1] += xv_ * w0_.y;           \
            acc[i_][2] += xv_ * w0_.z;  acc[i_][3] += xv_ * w0_.w;           \
            acc[i_][4] += xv_ * w1_.x;  acc[i_][5] += xv_ * w1_.y;           \
            acc[i_][6] += xv_ * w1_.z;  acc[i_][7] += xv_ * w1_.w;           \
        }                                                                    \
    }                                                                        \
} while (0)

    // Prologue: stage chunk 0, x chunks 0 and 1 in flight (36 VMEM).
    STAGE(ldsA, 0); SCHEDFENCE();
    XLOAD(x0, 0);
    XLOAD(x1, 1); SCHEDFENCE();

    // Phase 0: outstanding [stage0 x4, x0 x16, x1 x16] -> vmcnt(32)
    // completes stage0 (x RAW handled by compiler-inserted waits).
    WAITV(32); BAR();
    STAGE(ldsB, 1); SCHEDFENCE();
    COMPUTE(ldsA, x0); XLOAD(x0, 2); SCHEDFENCE();

#define PHASE(T, BUFC, BUFN, XS) do {                                        \
    WAITV(16); BAR();                                                        \
    STAGE(BUFN, (T) + 1); SCHEDFENCE();                                      \
    COMPUTE(BUFC, XS); XLOAD(XS, (T) + 2); SCHEDFENCE();                     \
} while (0)

    PHASE(1,  ldsB, ldsA, x1);
    PHASE(2,  ldsA, ldsB, x0);
    PHASE(3,  ldsB, ldsA, x1);
    PHASE(4,  ldsA, ldsB, x0);
    PHASE(5,  ldsB, ldsA, x1);
    PHASE(6,  ldsA, ldsB, x0);
    PHASE(7,  ldsB, ldsA, x1);
    PHASE(8,  ldsA, ldsB, x0);
    PHASE(9,  ldsB, ldsA, x1);
    PHASE(10, ldsA, ldsB, x0);
    PHASE(11, ldsB, ldsA, x1);
    PHASE(12, ldsA, ldsB, x0);
    PHASE(13, ldsB, ldsA, x1);

    // Phase 14: stage chunk 15, no further x.
    WAITV(16); BAR();
    STAGE(ldsB, 15); SCHEDFENCE();
    COMPUTE(ldsA, x0); SCHEDFENCE();

    // Phase 15: drain, compute last chunk.
    WAITV(0); BAR();
    COMPUTE(ldsB, x1);

    // Epilogue: bias + coalesced store.
    const float4 b0v = *reinterpret_cast<const float4*>(bias + (size_t)l * kC + d0);
    const float4 b1v = *reinterpret_cast<const float4*>(bias + (size_t)l * kC + d0 + 4);
    const float bv[kND] = {b0v.x, b0v.y, b0v.z, b0v.w, b1v.x, b1v.y, b1v.z, b1v.w};

#pragma unroll
    for (int i = 0; i < kNB; ++i) {
        float* op = out + (size_t)(b0 + i) * (kC * kL) + l;
#pragma unroll
        for (int j = 0; j < kND; ++j)
            op[(size_t)(d0 + j) * kL] = acc[i][j] + bv[j];  // coalesced over l
    }

#undef STAGE
#undef XLOAD
#undef COMPUTE
#undef PHASE
}

}  // namespace

extern "C" void kernel_launch(void* const* d_in, const int* in_sizes, int n_in,
                              void* d_out, int out_size, void* d_ws, size_t ws_size,
                              hipStream_t stream) {
    // inputs: 0=x (B,C,H,W) fp32, 1=px (unused), 2=weight (L*C, C) fp32,
    //         3=bias (L*C) fp32
    const float* x    = (const float*)d_in[0];
    const float* wgt  = (const float*)d_in[2];
    const float* bias = (const float*)d_in[3];
    float* out = (float*)d_out;

    dim3 grid(kL / 64, 128 / kNB);  // 64 x 16 = 1024 blocks = 4/CU
    dim3 block(256);
    hipLaunchKernelGGL(dyna_dec, grid, block, 0, stream, x, wgt, bias, out);
}